// Round 16
// baseline (245.599 us; speedup 1.0000x reference)
//
#include <hip/hip_runtime.h>
#include <hip/hip_bf16.h>
#include <math.h>

// Problem constants
constexpr int S   = 2048;
constexpr int D   = 2048;
constexpr int H   = 16;
constexpr int KVH = 4;
constexpr int HD  = 128;
constexpr int NQ  = H * HD;      // 2048
constexpr int NKV = KVH * HD;    // 512
constexpr int N3  = NQ + 2 * NKV; // 3072
constexpr int GROUPS = H / KVH;   // 4
constexpr float SCALE = 0.088388347648318447f; // 128^-0.5
constexpr int HEAVY  = 204;
constexpr int RECENT = 204;
constexpr int SKEEP  = S - RECENT;  // 1844
constexpr int MASKC  = S + 1;       // 2049
constexpr int NTILE_H = 528;        // 32*33/2 causal tiles per head

typedef short bf16x8 __attribute__((ext_vector_type(8)));
typedef _Float16 f16x8 __attribute__((ext_vector_type(8)));
typedef unsigned short ushort8 __attribute__((ext_vector_type(8)));
typedef unsigned short ushort4v __attribute__((ext_vector_type(4)));
typedef float f32x4 __attribute__((ext_vector_type(4)));

__device__ __forceinline__ unsigned short f2b(float x) {
  __hip_bfloat16 h = __float2bfloat16(x);
  return *(unsigned short*)&h;
}
__device__ __forceinline__ float b2f(unsigned short u) {
  __hip_bfloat16 h = *(__hip_bfloat16*)&u;
  return __bfloat162float(h);
}
__device__ __forceinline__ unsigned short f2h(float x) {
  _Float16 h = (_Float16)x;
  return *(unsigned short*)&h;
}

// async global -> LDS, 16B per lane; LDS dest = wave-uniform base + lane*16
__device__ __forceinline__ void gload16(const unsigned short* g,
                                        unsigned short* l) {
  __builtin_amdgcn_global_load_lds(
      (const __attribute__((address_space(1))) unsigned int*)g,
      (__attribute__((address_space(3))) unsigned int*)l, 16, 0, 0);
}

// ---------------------------------------------------------------------------
// prep_all (verified R18): hs and q/k/v weights stored as SINGLE fp16;
// o_w transpose stays bf16 (oproj GEMM is bf16).
// ---------------------------------------------------------------------------
__device__ __forceinline__ void split_wT_dev(
    const float* __restrict__ in, unsigned short* __restrict__ oh,
    int K, int N, int rowOff, int ldOut, int bx, int by, float (*Lt)[65]) {
  const int n0 = bx * 64, k0 = by * 64;
  const int t = threadIdx.x;
  const int cq = t & 15, r4 = t >> 4;
#pragma unroll
  for (int i = 0; i < 4; ++i) {
    int r = r4 + i * 16;
    float4 v = *(const float4*)&in[(size_t)(k0 + r) * N + n0 + cq * 4];
    Lt[cq * 4 + 0][r] = v.x;
    Lt[cq * 4 + 1][r] = v.y;
    Lt[cq * 4 + 2][r] = v.z;
    Lt[cq * 4 + 3][r] = v.w;
  }
  __syncthreads();
#pragma unroll
  for (int i = 0; i < 4; ++i) {
    int rr = r4 + i * 16;
    size_t base = (size_t)(rowOff + n0 + rr) * ldOut + k0 + cq * 4;
    ushort4v hv;
#pragma unroll
    for (int j = 0; j < 4; ++j) hv[j] = f2h(Lt[rr][cq * 4 + j]);  // fp16
    *(ushort4v*)&oh[base] = hv;
  }
}

__global__ __launch_bounds__(256) void prep_all(
    const float* __restrict__ hs, const float* __restrict__ q_w,
    const float* __restrict__ k_w, const float* __restrict__ v_w,
    const float* __restrict__ o_w, const float* __restrict__ qb,
    const float* __restrict__ kb, const float* __restrict__ vb,
    unsigned short* __restrict__ hsh,
    unsigned short* __restrict__ WTh,
    unsigned short* __restrict__ OTh, float* __restrict__ bcat) {
  __shared__ float Lt[64][65];
  const int b = blockIdx.x;
  if (b < 1024) {
    split_wT_dev(q_w, WTh, D, NQ, 0, D, b & 31, b >> 5, Lt);
  } else if (b < 1280) {
    int b2 = b - 1024;
    split_wT_dev(k_w, WTh, D, NKV, NQ, D, b2 & 7, b2 >> 3, Lt);
  } else if (b < 1536) {
    int b2 = b - 1280;
    split_wT_dev(v_w, WTh, D, NKV, NQ + NKV, D, b2 & 7, b2 >> 3, Lt);
  } else if (b < 2560) {
    int b2 = b - 1536;
    const int n0 = (b2 & 31) * 64, k0 = (b2 >> 5) * 64;
    const int t = threadIdx.x;
    const int cq = t & 15, r4 = t >> 4;
#pragma unroll
    for (int i = 0; i < 4; ++i) {
      int r = r4 + i * 16;
      float4 v = *(const float4*)&o_w[(size_t)(k0 + r) * D + n0 + cq * 4];
      Lt[cq * 4 + 0][r] = v.x;
      Lt[cq * 4 + 1][r] = v.y;
      Lt[cq * 4 + 2][r] = v.z;
      Lt[cq * 4 + 3][r] = v.w;
    }
    __syncthreads();
#pragma unroll
    for (int i = 0; i < 4; ++i) {
      int rr = r4 + i * 16;
      size_t base = (size_t)(n0 + rr) * NQ + k0 + cq * 4;
      ushort4v hv;
#pragma unroll
      for (int j = 0; j < 4; ++j) hv[j] = f2b(Lt[rr][cq * 4 + j]);  // bf16
      *(ushort4v*)&OTh[base] = hv;
    }
  } else if (b < 3072) {
    int b2 = b - 2560;
    size_t base = (size_t)b2 * 8192;
    for (int i = threadIdx.x * 4; i < 8192; i += 1024) {
      float4 v = *(const float4*)&hs[base + i];
      ushort4v hv;
      hv[0] = f2h(v.x);
      hv[1] = f2h(v.y);
      hv[2] = f2h(v.z);
      hv[3] = f2h(v.w);
      *(ushort4v*)&hsh[base + i] = hv;
    }
  } else {
    int i = (b - 3072) * 256 + threadIdx.x;
    if (i < NQ) bcat[i] = qb[i];
    else if (i < NQ + NKV) bcat[i] = kb[i - NQ];
    else if (i < N3) bcat[i] = vb[i - NQ - NKV];
  }
}

// ---------------------------------------------------------------------------
// QKV GEMM (verified R22): fp16 inputs, 1-term MFMA, tile 128x96, BK=64
// (two 32-col panels per buffer), double-buffered, 2 blocks/CU.
// ---------------------------------------------------------------------------
__global__ __launch_bounds__(256) void gemm_qkv(
    const unsigned short* __restrict__ Ah,
    const unsigned short* __restrict__ Bh,
    const float* __restrict__ bias,
    unsigned short* __restrict__ Qh,
    unsigned short* __restrict__ Kh,
    unsigned short* __restrict__ Vt, int M, int N, int K) {
  __shared__ __align__(16) unsigned short sA[2][128 * 64];  // 2 panels/buf
  __shared__ __align__(16) unsigned short sB[2][96 * 64];
  const int tid = threadIdx.x;
  const int lane = tid & 63, wave = tid >> 6;
  const int wm = wave >> 1, wn = wave & 1;
  const int quad = lane >> 4, l16 = lane & 15;
  const int m0 = blockIdx.y * 128, n0 = blockIdx.x * 96;

  const int lr = lane >> 2;
  const int gj = (lane & 3) ^ (lr & 3);

  f32x4 acc[4][3];
#pragma unroll
  for (int i = 0; i < 4; ++i)
#pragma unroll
    for (int j = 0; j < 3; ++j) acc[i][j] = (f32x4){0.f, 0.f, 0.f, 0.f};

  // prologue: stage k=[0,64) into buffer 0 (two 32-col panels)
#pragma unroll
  for (int p = 0; p < 2; ++p) {
#pragma unroll
    for (int it = 0; it < 2; ++it) {
      int c = wave * 2 + it;
      int r = c * 16 + lr;
      size_t ga = (size_t)(m0 + r) * K + p * 32 + gj * 8;
      gload16(&Ah[ga], &sA[0][p * 4096 + c * 512]);
    }
#pragma unroll
    for (int it = 0; it < 2; ++it) {
      int c = wave + it * 4;
      if (c < 6) {
        int r = c * 16 + lr;
        size_t gb = (size_t)(n0 + r) * K + p * 32 + gj * 8;
        gload16(&Bh[gb], &sB[0][p * 3072 + c * 512]);
      }
    }
  }
  __syncthreads();

  int cur = 0;
  for (int k0 = 0; k0 < K; k0 += 64, cur ^= 1) {
    if (k0 + 64 < K) {
      const int kn = k0 + 64;
#pragma unroll
      for (int p = 0; p < 2; ++p) {
#pragma unroll
        for (int it = 0; it < 2; ++it) {
          int c = wave * 2 + it;
          int r = c * 16 + lr;
          size_t ga = (size_t)(m0 + r) * K + kn + p * 32 + gj * 8;
          gload16(&Ah[ga], &sA[cur ^ 1][p * 4096 + c * 512]);
        }
#pragma unroll
        for (int it = 0; it < 2; ++it) {
          int c = wave + it * 4;
          if (c < 6) {
            int r = c * 16 + lr;
            size_t gb = (size_t)(n0 + r) * K + kn + p * 32 + gj * 8;
            gload16(&Bh[gb], &sB[cur ^ 1][p * 3072 + c * 512]);
          }
        }
      }
    }
    const int sw = (quad ^ (l16 & 3)) * 8;
#pragma unroll
    for (int kk = 0; kk < 2; ++kk) {  // k-ascending panels -> bit-identical
      f16x8 fa[4], fb[3];
#pragma unroll
      for (int i = 0; i < 4; ++i)
        fa[i] = *(f16x8*)&sA[cur][kk * 4096 + (wm * 64 + i * 16 + l16) * 32 + sw];
#pragma unroll
      for (int j = 0; j < 3; ++j)
        fb[j] = *(f16x8*)&sB[cur][kk * 3072 + (wn * 48 + j * 16 + l16) * 32 + sw];
#pragma unroll
      for (int i = 0; i < 4; ++i)
#pragma unroll
        for (int j = 0; j < 3; ++j)
          acc[i][j] = __builtin_amdgcn_mfma_f32_16x16x32_f16(fa[i], fb[j], acc[i][j], 0, 0, 0);
    }
    __syncthreads();
  }
#pragma unroll
  for (int i = 0; i < 4; ++i) {
#pragma unroll
    for (int j = 0; j < 3; ++j) {
      int row = m0 + wm * 64 + i * 16 + quad * 4;
      int col = n0 + wn * 48 + j * 16 + l16;
      float bv = bias[col];
      if (col < NQ) {
#pragma unroll
        for (int r = 0; r < 4; ++r) {
          size_t o = (size_t)(row + r) * NQ + col;
          Qh[o] = f2h(acc[i][j][r] + bv);  // fp16 Q
        }
      } else if (col < NQ + NKV) {
        int c = col - NQ;
        size_t ob = ((size_t)(c >> 7) * S) * HD + (c & 127);
#pragma unroll
        for (int r = 0; r < 4; ++r) {
          size_t o = ob + (size_t)(row + r) * HD;
          Kh[o] = f2h(acc[i][j][r] + bv);  // fp16 K
        }
      } else {
        int c = col - NQ - NKV;
        ushort4v pv;
#pragma unroll
        for (int r = 0; r < 4; ++r) pv[r] = f2h(acc[i][j][r] + bv);  // fp16 V
        *(ushort4v*)&Vt[((size_t)(c >> 7) * HD + (c & 127)) * S + row] = pv;
      }
    }
  }
}

// ---------------------------------------------------------------------------
// fused post-attention kernel (verified R21): oproj 128x64 (512 blocks,
// 2/CU) + 464 cur blocks.
// ---------------------------------------------------------------------------
__global__ __launch_bounds__(256) void fuse_post(
    const unsigned short* __restrict__ AOh, const unsigned short* __restrict__ OTh,
    float* __restrict__ C,
    const unsigned short* __restrict__ Eg, const float* __restrict__ lbuf,
    float* __restrict__ cur) {
  __shared__ __align__(16) unsigned char smem[24576];
  const int bid = blockIdx.x;
  const int tid = threadIdx.x;
  if (bid < 512) {
    unsigned short* sAb = (unsigned short*)smem;        // 2 x 4096 ushort
    unsigned short* sBb = (unsigned short*)smem + 8192; // 2 x 2048 ushort
    const int lane = tid & 63, wave = tid >> 6;
    const int wm = wave >> 1, wn = wave & 1;
    const int quad = lane >> 4, l16 = lane & 15;
    const int m0 = (bid >> 5) * 128, n0 = (bid & 31) * 64;
    const int K = NQ, N = D;
    const int lr = lane >> 2;
    const int gj = (lane & 3) ^ (lr & 3);

    f32x4 acc[4][2];
#pragma unroll
    for (int i = 0; i < 4; ++i)
#pragma unroll
      for (int j = 0; j < 2; ++j) acc[i][j] = (f32x4){0.f, 0.f, 0.f, 0.f};

#pragma unroll
    for (int it = 0; it < 2; ++it) {
      int c = wave * 2 + it;
      int r = c * 16 + lr;
      size_t ga = (size_t)(m0 + r) * K + gj * 8;
      gload16(&AOh[ga], &sAb[c * 512]);
    }
    {
      int r = wave * 16 + lr;
      size_t gb = (size_t)(n0 + r) * K + gj * 8;
      gload16(&OTh[gb], &sBb[wave * 512]);
    }
    __syncthreads();

    int cb = 0;
    for (int k0 = 0; k0 < K; k0 += 32, cb ^= 1) {
      if (k0 + 32 < K) {
        const int kn = k0 + 32;
#pragma unroll
        for (int it = 0; it < 2; ++it) {
          int c = wave * 2 + it;
          int r = c * 16 + lr;
          size_t ga = (size_t)(m0 + r) * K + kn + gj * 8;
          gload16(&AOh[ga], &sAb[(cb ^ 1) * 4096 + c * 512]);
        }
        {
          int r = wave * 16 + lr;
          size_t gb = (size_t)(n0 + r) * K + kn + gj * 8;
          gload16(&OTh[gb], &sBb[(cb ^ 1) * 2048 + wave * 512]);
        }
      }
      const int sw = (quad ^ (l16 & 3)) * 8;
      bf16x8 fa[4], fb[2];
#pragma unroll
      for (int i = 0; i < 4; ++i)
        fa[i] = *(bf16x8*)&sAb[cb * 4096 + (wm * 64 + i * 16 + l16) * 32 + sw];
#pragma unroll
      for (int j = 0; j < 2; ++j)
        fb[j] = *(bf16x8*)&sBb[cb * 2048 + (wn * 32 + j * 16 + l16) * 32 + sw];
#pragma unroll
      for (int i = 0; i < 4; ++i)
#pragma unroll
        for (int j = 0; j < 2; ++j)
          acc[i][j] = __builtin_amdgcn_mfma_f32_16x16x32_bf16(fa[i], fb[j], acc[i][j], 0, 0, 0);
      __syncthreads();
    }
#pragma unroll
    for (int i = 0; i < 4; ++i)
#pragma unroll
      for (int j = 0; j < 2; ++j) {
        int row = m0 + wm * 64 + i * 16 + quad * 4;
        int col = n0 + wn * 32 + j * 16 + l16;
#pragma unroll
        for (int r = 0; r < 4; ++r)
          C[(size_t)(row + r) * N + col] = acc[i][j][r];
      }
  } else {
    const int bid2 = bid - 512;
    const int kt = bid2 % 29;   // 0..28
    const int h  = bid2 / 29;   // 0..15
    const int c8 = tid & 7, qg = tid >> 3;
    float acc[8];
#pragma unroll
    for (int j = 0; j < 8; ++j) acc[j] = 0.f;
    const size_t hb = (size_t)h * NTILE_H;
    for (int qt = kt; qt < 32; ++qt) {
      size_t tb = (hb + (size_t)(qt * (qt + 1) / 2) + kt) * 4096;
      float li0 = 1.0f / lbuf[h * S + qt * 64 + qg];
      float li1 = 1.0f / lbuf[h * S + qt * 64 + 32 + qg];
      f16x8 e0 = *(const f16x8*)&Eg[tb + (size_t)qg * 64 + c8 * 8];
      f16x8 e1 = *(const f16x8*)&Eg[tb + (size_t)(32 + qg) * 64 + c8 * 8];
#pragma unroll
      for (int j = 0; j < 8; ++j)
        acc[j] += (float)e0[j] * li0 + (float)e1[j] * li1;
    }
    float (*red)[8] = (float(*)[8])smem;
#pragma unroll
    for (int j = 0; j < 8; ++j) red[tid][j] = acc[j];
    __syncthreads();
    if (tid < 64) {
      int cc = tid >> 3, j = tid & 7;
      float s = 0.f;
#pragma unroll
      for (int g = 0; g < 32; ++g) s += red[cc + 8 * g][j];
      cur[h * S + kt * 64 + cc * 8 + j] = s;
    }
  }
}

// ---------------------------------------------------------------------------
// Plain bf16 GEMM (oproj) — FALLBACK only (no-E path).
// ---------------------------------------------------------------------------
__global__ __launch_bounds__(256) void gemm_bf16(
    const unsigned short* __restrict__ Ah, const unsigned short* __restrict__ Bh,
    float* __restrict__ C, int M, int N, int K) {
  __shared__ __align__(16) unsigned short sA[2][128 * 32];
  __shared__ __align__(16) unsigned short sB[2][128 * 32];
  const int tid = threadIdx.x;
  const int lane = tid & 63, wave = tid >> 6;
  const int wm = wave >> 1, wn = wave & 1;
  const int quad = lane >> 4, l16 = lane & 15;
  const int m0 = blockIdx.y * 128, n0 = blockIdx.x * 128;
  const int lr = lane >> 2;
  const int gj = (lane & 3) ^ (lr & 3);

  f32x4 acc[4][4];
#pragma unroll
  for (int i = 0; i < 4; ++i)
#pragma unroll
    for (int j = 0; j < 4; ++j) acc[i][j] = (f32x4){0.f, 0.f, 0.f, 0.f};

#pragma unroll
  for (int it = 0; it < 2; ++it) {
    int c = wave * 2 + it;
    int r = c * 16 + lr;
    size_t ga = (size_t)(m0 + r) * K + gj * 8;
    size_t gb = (size_t)(n0 + r) * K + gj * 8;
    gload16(&Ah[ga], &sA[0][c * 512]);
    gload16(&Bh[gb], &sB[0][c * 512]);
  }
  __syncthreads();

  int cur = 0;
  for (int k0 = 0; k0 < K; k0 += 32, cur ^= 1) {
    if (k0 + 32 < K) {
      const int kn = k0 + 32;
#pragma unroll
      for (int it = 0; it < 2; ++it) {
        int c = wave * 2 + it;
        int r = c * 16 + lr;
        size_t ga = (size_t)(m0 + r) * K + kn + gj * 8;
        size_t gb = (size_t)(n0 + r) * K + kn + gj * 8;
        gload16(&Ah[ga], &sA[cur ^ 1][c * 512]);
        gload16(&Bh[gb], &sB[cur ^ 1][c * 512]);
      }
    }
    const int sw = (quad ^ (l16 & 3)) * 8;
    bf16x8 fa[4], fb[4];
#pragma unroll
    for (int i = 0; i < 4; ++i) {
      fa[i] = *(bf16x8*)&sA[cur][(wm * 64 + i * 16 + l16) * 32 + sw];
      fb[i] = *(bf16x8*)&sB[cur][(wn * 64 + i * 16 + l16) * 32 + sw];
    }
#pragma unroll
    for (int i = 0; i < 4; ++i)
#pragma unroll
      for (int j = 0; j < 4; ++j)
        acc[i][j] = __builtin_amdgcn_mfma_f32_16x16x32_bf16(fa[i], fb[j], acc[i][j], 0, 0, 0);
    __syncthreads();
  }
#pragma unroll
  for (int i = 0; i < 4; ++i)
#pragma unroll
    for (int j = 0; j < 4; ++j) {
      int row = m0 + wm * 64 + i * 16 + quad * 4;
      int col = n0 + wn * 64 + j * 16 + l16;
#pragma unroll
      for (int r = 0; r < 4; ++r)
        C[(size_t)(row + r) * N + col] = acc[i][j][r];
    }
}

// ---------------------------------------------------------------------------
// MFMA flash attention. R24 (= R23 with the LDS pointer-array compile fix:
// buffer select via integer offset, no addrspace pointer arrays).
// Double-buffered K/V LDS: stage tile kt+1 into buf^1 BEFORE computing from
// buf[cb]; ONE barrier per k-tile (was 2), staging overlaps compute.
// LDS 80.9KB -> 2 blocks/CU. MFMA operand values and accumulation order
// unchanged -> bit-identical outputs.
// ---------------------------------------------------------------------------
__global__ __launch_bounds__(256) void attn_mfma(
    const unsigned short* __restrict__ Qh,
    const unsigned short* __restrict__ Kh,
    const unsigned short* __restrict__ Vt, unsigned short* __restrict__ AOh,
    float* __restrict__ lbuf, unsigned short* __restrict__ Eg) {
  const int x = blockIdx.x;
  const int base = x & 255;
  const int qt0 = base & 31, h0 = base >> 5;
  const int qt = (x < 256) ? qt0 : 31 - qt0;
  const int h  = (x < 256) ? h0 : h0 + 8;
  const int kvh = h / GROUPS;
  const int tid = threadIdx.x;
  const int lane = tid & 63, w = tid >> 6;
  const int quad = lane >> 4, l16 = lane & 15;
  const int q0 = qt * 64;

  // 2x(8704+9216) + 4608 = 40448 ushort = 80896 B; 2 blocks/CU
  // buf b: K at smem + b*17920, V at smem + b*17920 + 8704; P at smem+35840.
  __shared__ __align__(16) unsigned short smem[40448];
  unsigned short* sQ = smem;            // 64 x 136 (reuses buf0 K region)
  unsigned short* sP = smem + 35840;    // 4 waves x 16 x 72 (4608)

  const size_t ebase = ((size_t)h * NTILE_H + (size_t)(qt * (qt + 1) / 2)) * 4096;

  // ---- load Q via LDS (buf0 K region), read fragments ----
#pragma unroll
  for (int it = 0; it < 4; ++it) {
    int idx = tid + it * 256;
    int r = idx >> 4, c8 = idx & 15;
    size_t g = (size_t)(q0 + r) * NQ + h * HD + c8 * 8;
    *(ushort8*)&sQ[r * 136 + c8 * 8] = *(const ushort8*)&Qh[g];
  }
  __syncthreads();
  f16x8 fq[4];
#pragma unroll
  for (int d4 = 0; d4 < 4; ++d4)
    fq[d4] = *(f16x8*)&sQ[(w * 16 + l16) * 136 + d4 * 32 + quad * 8];
  __syncthreads();  // all Q fragment reads done before buf0 is reused for K

  // ---- prologue: regs=tile0 -> buf0; regs=tile1 ----
  ushort8 pK[4], pV[4];
#pragma unroll
  for (int it = 0; it < 4; ++it) {
    int idx = tid + it * 256;
    int r = idx >> 4, c8 = idx & 15;
    pK[it] = *(const ushort8*)&Kh[((size_t)kvh * S + r) * HD + c8 * 8];
  }
#pragma unroll
  for (int it = 0; it < 4; ++it) {
    int idx = tid + it * 256;
    int d = idx >> 3, c8 = idx & 7;
    pV[it] = *(const ushort8*)&Vt[((size_t)kvh * HD + d) * S + c8 * 8];
  }
#pragma unroll
  for (int it = 0; it < 4; ++it) {
    int idx = tid + it * 256;
    int r = idx >> 4, c8 = idx & 15;
    *(ushort8*)&smem[r * 136 + c8 * 8] = pK[it];
  }
#pragma unroll
  for (int it = 0; it < 4; ++it) {
    int idx = tid + it * 256;
    int d = idx >> 3, c8 = idx & 7;
    *(ushort8*)&smem[8704 + d * 72 + c8 * 8] = pV[it];
  }
  if (qt >= 1) {
#pragma unroll
    for (int it = 0; it < 4; ++it) {
      int idx = tid + it * 256;
      int r = idx >> 4, c8 = idx & 15;
      pK[it] = *(const ushort8*)&Kh[((size_t)kvh * S + 64 + r) * HD + c8 * 8];
    }
#pragma unroll
    for (int it = 0; it < 4; ++it) {
      int idx = tid + it * 256;
      int d = idx >> 3, c8 = idx & 7;
      pV[it] = *(const ushort8*)&Vt[((size_t)kvh * HD + d) * S + 64 + c8 * 8];
    }
  }
  __syncthreads();

  f32x4 O[8];
#pragma unroll
  for (int jn = 0; jn < 8; ++jn) O[jn] = (f32x4){0.f, 0.f, 0.f, 0.f};
  float l_[4] = {0.f, 0.f, 0.f, 0.f};  // per-lane partials (reduced after loop)

  const int row_l = w * 16 + quad * 4;
  const int wbase = w * 1152;

  for (int kt = 0; kt <= qt; ++kt) {
    const int cb = kt & 1;
    const int curOff = cb ? 17920 : 0;
    const int nxtOff = cb ? 0 : 17920;
    // stage tile kt+1 (regs) into buf^1 — overlaps with compute below;
    // prefetch tile kt+2 into regs.
    if (kt + 1 <= qt) {
      unsigned short* dK = smem + nxtOff;
      unsigned short* dV = smem + nxtOff + 8704;
#pragma unroll
      for (int it = 0; it < 4; ++it) {
        int idx = tid + it * 256;
        int r = idx >> 4, c8 = idx & 15;
        *(ushort8*)&dK[r * 136 + c8 * 8] = pK[it];
      }
#pragma unroll
      for (int it = 0; it < 4; ++it) {
        int idx = tid + it * 256;
        int d = idx >> 3, c8 = idx & 7;
        *(ushort8*)&dV[d * 72 + c8 * 8] = pV[it];
      }
      if (kt + 2 <= qt) {
#pragma unroll
        for (int it = 0; it < 4; ++it) {
          int idx = tid + it * 256;
          int r = idx >> 4, c8 = idx & 15;
          size_t g = ((size_t)kvh * S + (kt + 2) * 64 + r) * HD + c8 * 8;
          pK[it] = *(const ushort8*)&Kh[g];
        }
#pragma unroll
        for (int it = 0; it < 4; ++it) {
          int idx = tid + it * 256;
          int d = idx >> 3, c8 = idx & 7;
          size_t g = ((size_t)kvh * HD + d) * S + (kt + 2) * 64 + c8 * 8;
          pV[it] = *(const ushort8*)&Vt[g];
        }
      }
    }

    const unsigned short* sK  = smem + curOff;
    const unsigned short* sVt = smem + curOff + 8704;

    f32x4 sc[4];
#pragma unroll
    for (int j = 0; j < 4; ++j) sc[j] = (f32x4){0.f, 0.f, 0.f, 0.f};
#pragma unroll
    for (int d4 = 0; d4 < 4; ++d4) {
#pragma unroll
      for (int j = 0; j < 4; ++j) {
        f16x8 bk = *(const f16x8*)&sK[(j * 16 + l16) * 136 + d4 * 32 + quad * 8];
        sc[j] = __builtin_amdgcn_mfma_f32_16x16x32_f16(fq[d4], bk, sc[j], 0, 0, 0);
      }
    }
    const bool diag = (kt == qt);
#pragma unroll
    for (int j = 0; j < 4; ++j) {
      int col_l = j * 16 + l16;
#pragma unroll
      for (int r = 0; r < 4; ++r) {
        float v = sc[j][r] * SCALE;
        if (diag && col_l > row_l + r) v = -INFINITY;
        float p = __expf(v);
        sc[j][r] = p;
        l_[r] += p;
      }
    }
#pragma unroll
    for (int j = 0; j < 4; ++j)
#pragma unroll
      for (int r = 0; r < 4; ++r)
        sP[wbase + (quad * 4 + r) * 72 + j * 16 + l16] = f2h(sc[j][r]);  // fp16 P

    if (Eg) {
      size_t tb = ebase + (size_t)kt * 4096;
#pragma unroll
      for (int it2 = 0; it2 < 2; ++it2) {
        int ci = lane + it2 * 64;
        int row = ci >> 3, cc = ci & 7;
        *(ushort8*)&Eg[tb + (size_t)(w * 16 + row) * 64 + cc * 8] =
            *(ushort8*)&sP[wbase + row * 72 + cc * 8];
      }
    }

    f16x8 ap0 = *(f16x8*)&sP[wbase + l16 * 72 + quad * 8];
    f16x8 ap1 = *(f16x8*)&sP[wbase + l16 * 72 + 32 + quad * 8];
#pragma unroll
    for (int jn = 0; jn < 8; ++jn) {
      f16x8 bv0 = *(const f16x8*)&sVt[(jn * 16 + l16) * 72 + quad * 8];
      f16x8 bv1 = *(const f16x8*)&sVt[(jn * 16 + l16) * 72 + 32 + quad * 8];
      O[jn] = __builtin_amdgcn_mfma_f32_16x16x32_f16(ap0, bv0, O[jn], 0, 0, 0);
      O[jn] = __builtin_amdgcn_mfma_f32_16x16x32_f16(ap1, bv1, O[jn], 0, 0, 0);
    }
    __syncthreads();  // single barrier: buf^1 writes visible; buf[cb] reads done
  }
  // single lane-reduce of l partials (within 16-lane groups)
#pragma unroll
  for (int off = 1; off < 16; off <<= 1)
#pragma unroll
    for (int r = 0; r < 4; ++r) l_[r] += __shfl_xor(l_[r], off);
  float linv[4];
#pragma unroll
  for (int r = 0; r < 4; ++r) linv[r] = 1.0f / l_[r];
#pragma unroll
  for (int jn = 0; jn < 8; ++jn)
#pragma unroll
    for (int r = 0; r < 4; ++r)
      AOh[(size_t)(q0 + row_l + r) * NQ + h * HD + jn * 16 + l16] =
          f2b(O[jn][r] * linv[r]);
  if (l16 == 0) {
#pragma unroll
    for (int r = 0; r < 4; ++r)
      lbuf[h * S + q0 + row_l + r] = l_[r];
  }
}

// ---------------------------------------------------------------------------
// MFMA cur pass (FALLBACK when workspace too small for E buffer), fp16 Q/K.
// ---------------------------------------------------------------------------
__global__ __launch_bounds__(256) void cur_mfma(
    const unsigned short* __restrict__ Qh,
    const unsigned short* __restrict__ Kh,
    const float* __restrict__ lbuf, float* __restrict__ cur) {
  const int x = blockIdx.x;
  const int base = x & 255;
  const int kt0 = base & 31, h0 = base >> 5;
  const int kt = (x < 256) ? kt0 : 31 - kt0;
  const int h  = (x < 256) ? h0 : h0 + 8;
  const int kvh = h / GROUPS;
  const int tid = threadIdx.x;
  const int lane = tid & 63, w = tid >> 6;
  const int quad = lane >> 4, l16 = lane & 15;

  __shared__ __align__(16) unsigned short sKh[8704];
  __shared__ __align__(16) unsigned short sQh[8704];
  __shared__ float slinv[64];

#pragma unroll
  for (int it = 0; it < 4; ++it) {
    int idx = tid + it * 256;
    int r = idx >> 4, c8 = idx & 15;
    size_t g = ((size_t)kvh * S + kt * 64 + r) * HD + c8 * 8;
    *(ushort8*)&sKh[r * 136 + c8 * 8] = *(const ushort8*)&Kh[g];
  }
  __syncthreads();
  f16x8 fk[4];
#pragma unroll
  for (int d4 = 0; d4 < 4; ++d4)
    fk[d4] = *(f16x8*)&sKh[(w * 16 + l16) * 136 + d4 * 32 + quad * 8];

  const int krow_l = w * 16 + quad * 4;
  float csum[4] = {0.f, 0.f, 0.f, 0.f};

  ushort8 pQ[4];
  float pli = 0.f;
#pragma unroll
  for (int it = 0; it < 4; ++it) {
    int idx = tid + it * 256;
    int r = idx >> 4, c8 = idx & 15;
    size_t g = (size_t)(kt * 64 + r) * NQ + h * HD + c8 * 8;
    pQ[it] = *(const ushort8*)&Qh[g];
  }
  if (tid < 64) pli = 1.0f / lbuf[h * S + kt * 64 + tid];

  for (int qt = kt; qt < S / 64; ++qt) {
    __syncthreads();
#pragma unroll
    for (int it = 0; it < 4; ++it) {
      int idx = tid + it * 256;
      int r = idx >> 4, c8 = idx & 15;
      *(ushort8*)&sQh[r * 136 + c8 * 8] = pQ[it];
    }
    if (tid < 64) slinv[tid] = pli;
    __syncthreads();
    if (qt + 1 < S / 64) {
#pragma unroll
      for (int it = 0; it < 4; ++it) {
        int idx = tid + it * 256;
        int r = idx >> 4, c8 = idx & 15;
        size_t g = (size_t)((qt + 1) * 64 + r) * NQ + h * HD + c8 * 8;
        pQ[it] = *(const ushort8*)&Qh[g];
      }
      if (tid < 64) pli = 1.0f / lbuf[h * S + (qt + 1) * 64 + tid];
    }
    f32x4 sc[4];
#pragma unroll
    for (int j = 0; j < 4; ++j) sc[j] = (f32x4){0.f, 0.f, 0.f, 0.f};
#pragma unroll
    for (int d4 = 0; d4 < 4; ++d4) {
#pragma unroll
      for (int j = 0; j < 4; ++j) {
        f16x8 bq = *(f16x8*)&sQh[(j * 16 + l16) * 136 + d4 * 32 + quad * 8];
        sc[j] = __builtin_amdgcn_mfma_f32_16x16x32_f16(fk[d4], bq, sc[j], 0, 0, 0);
      }
    }
    const bool diag = (qt == kt);
#pragma unroll
    for (int j = 0; j < 4; ++j) {
      int qcol_l = j * 16 + l16;
      float lv = slinv[qcol_l];
#pragma unroll
      for (int r = 0; r < 4; ++r) {
        float p = __expf(sc[j][r] * SCALE) * lv;
        if (diag && (krow_l + r) > qcol_l) p = 0.f;
        csum[r] += p;
      }
    }
  }
#pragma unroll
  for (int off = 1; off < 16; off <<= 1)
#pragma unroll
    for (int r = 0; r < 4; ++r) csum[r] += __shfl_xor(csum[r], off);
  if (l16 == 0) {
#pragma unroll
    for (int r = 0; r < 4; ++r)
      cur[h * S + kt * 64 + krow_l + r] = csum[r];
  }
}

// ---------------------------------------------------------------------------
// top-k + mask (verified R14).
// ---------------------------------------------------------------------------
__global__ __launch_bounds__(256) void topk_kernel(
    const float* __restrict__ cur, float* __restrict__ mask) {
  const int h = blockIdx.x;
  const int tid = threadIdx.x;
  const int lane = tid & 63, w = tid >> 6;
  __shared__ unsigned uv[SKEEP];
  __shared__ int redw[4];
  __shared__ int wsum[4];

  for (int i = tid; i < SKEEP; i += 256) uv[i] = __float_as_uint(cur[h * S + i]);
  __syncthreads();

  unsigned lo = 0u, hi = 0xffffffffu;
  while (lo < hi) {
    unsigned mid = (unsigned)((((unsigned long long)lo + hi) + 1ull) >> 1);
    int c = 0;
    for (int i = tid; i < SKEEP; i += 256) c += (uv[i] >= mid) ? 1 : 0;
#pragma unroll
    for (int off = 1; off < 64; off <<= 1) c += __shfl_xor(c, off);
    if (lane == 0) redw[w] = c;
    __syncthreads();
    int cnt = redw[0] + redw[1] + redw[2] + redw[3];
    __syncthreads();
    if (cnt >= HEAVY) lo = mid; else hi = mid - 1;
  }
  const unsigned vk = lo;
  int c = 0;
  for (int i = tid; i < SKEEP; i += 256) c += (uv[i] > vk) ? 1 : 0;
#pragma unroll
  for (int off = 1; off < 64; off <<= 1) c += __shfl_xor(c, off);
  if (lane == 0) redw[w] = c;
  __syncthreads();
  const int cgt = redw[0] + redw[1] + redw[2] + redw[3];
  const int rem = HEAVY - cgt;

  for (int j = tid; j < MASKC; j += 256)
    mask[(size_t)h * MASKC + j] = (j >= MASKC - RECENT) ? 1.0f : 0.0f;
  __syncthreads();
  for (int i = tid; i < SKEEP; i += 256)
    if (uv[i] > vk) mask[(size_t)h * MASKC + i] = 1.0f;

  // parallel tie fill: blocked partition preserves index order
  constexpr int PER = (SKEEP + 255) / 256;  // 8
  int i0 = tid * PER;
  int i1 = i0 + PER;
  if (i0 > SKEEP) i0 = SKEEP;
  if (i1 > SKEEP) i1 = SKEEP;
  int myT = 0;
  for (int i = i0; i < i1; ++i) myT += (uv[i] == vk) ? 1 : 0;
  int v = myT;
#pragma unroll
  for (int off = 1; off < 64; off <<= 1) {
    int t = __shfl_up(v, off);
    if (lane >= off) v += t;
  }
  if (lane == 63) wsum[w] = v;
  __syncthreads();
  int wOff = 0;
  for (int k = 0; k < w; ++k) wOff += wsum[k];
  int excl = wOff + v - myT;
  for (int i = i0; i < i1; ++i) {
    if (uv[i] == vk) {
      if (excl < rem) mask[(size_t)h * MASKC + i] = 1.0f;
      ++excl;
    }
  }
}

// ---------------------------------------------------------------------------
extern "C" void kernel_launch(void* const* d_in, const int* in_sizes, int n_in,
                              void* d_out, int out_size, void* d_ws,
                              size_t ws_size, hipStream_t stream) {
  const float* hs  = (const float*)d_in[0];
  const float* q_w = (const float*)d_in[1];
  const float* q_b = (const float*)d_in[2];
  const float* k_w = (const float*)d_in[3];
  const float* k_b = (const float*)d_in[4];
  const float* v_w = (const float*)d_in[5];
  const float* v_b = (const float*)d_in[6];
  const float* o_w = (const float*)d_in[7];

  char* ws = (char*)d_ws;
  unsigned short* Qh   = (unsigned short*)(ws + 0);
  unsigned short* Kh   = (unsigned short*)(ws + 16777216);
  unsigned short* Vt   = (unsigned short*)(ws + 20971520);
  unsigned short* AOh  = (unsigned short*)(ws + 25165824);
  float* lb   = (float*)(ws + 33685504);
  float* cur  = (float*)(ws + 33816576);
  float* bcat = (float*)(ws + 33947648);
  char* pool = ws + 33959936;
  unsigned short* hsh = (unsigned short*)pool;                 // 8.4 MB fp16
  unsigned short* WTh = (unsigned short*)(pool + 16777216);    // 12.6 MB fp16
  unsigned short* OTh = (unsigned short*)(pool + 41943040);    // 8.4 MB bf16

  // packed-causal E buffer (16 heads x 528 tiles x 64x64 fp16 = 69.2 MB)
  const size_t E_OFF = 84291584ull;               // end of pool
  const size_t E_SZ  = (size_t)H * NTILE_H * 4096 * 2;  // 69,206,016
  const bool use_e = (ws_size >= E_OFF + E_SZ);
  unsigned short* Eg = use_e ? (unsigned short*)(ws + E_OFF) : nullptr;

  float* outp  = (float*)d_out;
  float* maskp = outp + (size_t)S * D;

  dim3 blk(256);
  prep_all<<<dim3(3084), blk, 0, stream>>>(hs, q_w, k_w, v_w, o_w, q_b, k_b,
                                           v_b, hsh, WTh, OTh, bcat);
  gemm_qkv<<<dim3(N3 / 96, S / 128), blk, 0, stream>>>(
      hsh, WTh, bcat, Qh, Kh, Vt, S, N3, D);
  attn_mfma<<<dim3(512), blk, 0, stream>>>(Qh, Kh, Vt, AOh, lb, Eg);
  if (use_e) {
    fuse_post<<<dim3(512 + 29 * 16), blk, 0, stream>>>(AOh, OTh, outp, Eg, lb,
                                                       cur);
    topk_kernel<<<dim3(H), blk, 0, stream>>>(cur, maskp);
  } else {
    cur_mfma<<<dim3(512), blk, 0, stream>>>(Qh, Kh, lb, cur);
    topk_kernel<<<dim3(H), blk, 0, stream>>>(cur, maskp);
    gemm_bf16<<<dim3(D / 128, S / 128), blk, 0, stream>>>(AOh, OTh, outp, S, D,
                                                          NQ);
  }
}

// Round 17
// 242.657 us; speedup vs baseline: 1.0121x; 1.0121x over previous
//
#include <hip/hip_runtime.h>
#include <hip/hip_bf16.h>
#include <math.h>

// Problem constants
constexpr int S   = 2048;
constexpr int D   = 2048;
constexpr int H   = 16;
constexpr int KVH = 4;
constexpr int HD  = 128;
constexpr int NQ  = H * HD;      // 2048
constexpr int NKV = KVH * HD;    // 512
constexpr int N3  = NQ + 2 * NKV; // 3072
constexpr int GROUPS = H / KVH;   // 4
constexpr float SCALE = 0.088388347648318447f; // 128^-0.5
constexpr int HEAVY  = 204;
constexpr int RECENT = 204;
constexpr int SKEEP  = S - RECENT;  // 1844
constexpr int MASKC  = S + 1;       // 2049
constexpr int NTILE_H = 528;        // 32*33/2 causal tiles per head

typedef short bf16x8 __attribute__((ext_vector_type(8)));
typedef _Float16 f16x8 __attribute__((ext_vector_type(8)));
typedef unsigned short ushort8 __attribute__((ext_vector_type(8)));
typedef unsigned short ushort4v __attribute__((ext_vector_type(4)));
typedef float f32x4 __attribute__((ext_vector_type(4)));

__device__ __forceinline__ unsigned short f2b(float x) {
  __hip_bfloat16 h = __float2bfloat16(x);
  return *(unsigned short*)&h;
}
__device__ __forceinline__ float b2f(unsigned short u) {
  __hip_bfloat16 h = *(__hip_bfloat16*)&u;
  return __bfloat162float(h);
}
__device__ __forceinline__ unsigned short f2h(float x) {
  _Float16 h = (_Float16)x;
  return *(unsigned short*)&h;
}

// async global -> LDS, 16B per lane; LDS dest = wave-uniform base + lane*16
__device__ __forceinline__ void gload16(const unsigned short* g,
                                        unsigned short* l) {
  __builtin_amdgcn_global_load_lds(
      (const __attribute__((address_space(1))) unsigned int*)g,
      (__attribute__((address_space(3))) unsigned int*)l, 16, 0, 0);
}

// ---------------------------------------------------------------------------
// prep_all (verified R18): hs and q/k/v weights stored as SINGLE fp16;
// o_w transpose stays bf16 (oproj GEMM is bf16).
// ---------------------------------------------------------------------------
__device__ __forceinline__ void split_wT_dev(
    const float* __restrict__ in, unsigned short* __restrict__ oh,
    int K, int N, int rowOff, int ldOut, int bx, int by, float (*Lt)[65]) {
  const int n0 = bx * 64, k0 = by * 64;
  const int t = threadIdx.x;
  const int cq = t & 15, r4 = t >> 4;
#pragma unroll
  for (int i = 0; i < 4; ++i) {
    int r = r4 + i * 16;
    float4 v = *(const float4*)&in[(size_t)(k0 + r) * N + n0 + cq * 4];
    Lt[cq * 4 + 0][r] = v.x;
    Lt[cq * 4 + 1][r] = v.y;
    Lt[cq * 4 + 2][r] = v.z;
    Lt[cq * 4 + 3][r] = v.w;
  }
  __syncthreads();
#pragma unroll
  for (int i = 0; i < 4; ++i) {
    int rr = r4 + i * 16;
    size_t base = (size_t)(rowOff + n0 + rr) * ldOut + k0 + cq * 4;
    ushort4v hv;
#pragma unroll
    for (int j = 0; j < 4; ++j) hv[j] = f2h(Lt[rr][cq * 4 + j]);  // fp16
    *(ushort4v*)&oh[base] = hv;
  }
}

__global__ __launch_bounds__(256) void prep_all(
    const float* __restrict__ hs, const float* __restrict__ q_w,
    const float* __restrict__ k_w, const float* __restrict__ v_w,
    const float* __restrict__ o_w, const float* __restrict__ qb,
    const float* __restrict__ kb, const float* __restrict__ vb,
    unsigned short* __restrict__ hsh,
    unsigned short* __restrict__ WTh,
    unsigned short* __restrict__ OTh, float* __restrict__ bcat) {
  __shared__ float Lt[64][65];
  const int b = blockIdx.x;
  if (b < 1024) {
    split_wT_dev(q_w, WTh, D, NQ, 0, D, b & 31, b >> 5, Lt);
  } else if (b < 1280) {
    int b2 = b - 1024;
    split_wT_dev(k_w, WTh, D, NKV, NQ, D, b2 & 7, b2 >> 3, Lt);
  } else if (b < 1536) {
    int b2 = b - 1280;
    split_wT_dev(v_w, WTh, D, NKV, NQ + NKV, D, b2 & 7, b2 >> 3, Lt);
  } else if (b < 2560) {
    int b2 = b - 1536;
    const int n0 = (b2 & 31) * 64, k0 = (b2 >> 5) * 64;
    const int t = threadIdx.x;
    const int cq = t & 15, r4 = t >> 4;
#pragma unroll
    for (int i = 0; i < 4; ++i) {
      int r = r4 + i * 16;
      float4 v = *(const float4*)&o_w[(size_t)(k0 + r) * D + n0 + cq * 4];
      Lt[cq * 4 + 0][r] = v.x;
      Lt[cq * 4 + 1][r] = v.y;
      Lt[cq * 4 + 2][r] = v.z;
      Lt[cq * 4 + 3][r] = v.w;
    }
    __syncthreads();
#pragma unroll
    for (int i = 0; i < 4; ++i) {
      int rr = r4 + i * 16;
      size_t base = (size_t)(n0 + rr) * NQ + k0 + cq * 4;
      ushort4v hv;
#pragma unroll
      for (int j = 0; j < 4; ++j) hv[j] = f2b(Lt[rr][cq * 4 + j]);  // bf16
      *(ushort4v*)&OTh[base] = hv;
    }
  } else if (b < 3072) {
    int b2 = b - 2560;
    size_t base = (size_t)b2 * 8192;
    for (int i = threadIdx.x * 4; i < 8192; i += 1024) {
      float4 v = *(const float4*)&hs[base + i];
      ushort4v hv;
      hv[0] = f2h(v.x);
      hv[1] = f2h(v.y);
      hv[2] = f2h(v.z);
      hv[3] = f2h(v.w);
      *(ushort4v*)&hsh[base + i] = hv;
    }
  } else {
    int i = (b - 3072) * 256 + threadIdx.x;
    if (i < NQ) bcat[i] = qb[i];
    else if (i < NQ + NKV) bcat[i] = kb[i - NQ];
    else if (i < N3) bcat[i] = vb[i - NQ - NKV];
  }
}

// ---------------------------------------------------------------------------
// QKV GEMM (verified R22): fp16 inputs, 1-term MFMA, tile 128x96, BK=64
// (two 32-col panels per buffer), double-buffered, 2 blocks/CU.
// ---------------------------------------------------------------------------
__global__ __launch_bounds__(256) void gemm_qkv(
    const unsigned short* __restrict__ Ah,
    const unsigned short* __restrict__ Bh,
    const float* __restrict__ bias,
    unsigned short* __restrict__ Qh,
    unsigned short* __restrict__ Kh,
    unsigned short* __restrict__ Vt, int M, int N, int K) {
  __shared__ __align__(16) unsigned short sA[2][128 * 64];  // 2 panels/buf
  __shared__ __align__(16) unsigned short sB[2][96 * 64];
  const int tid = threadIdx.x;
  const int lane = tid & 63, wave = tid >> 6;
  const int wm = wave >> 1, wn = wave & 1;
  const int quad = lane >> 4, l16 = lane & 15;
  const int m0 = blockIdx.y * 128, n0 = blockIdx.x * 96;

  const int lr = lane >> 2;
  const int gj = (lane & 3) ^ (lr & 3);

  f32x4 acc[4][3];
#pragma unroll
  for (int i = 0; i < 4; ++i)
#pragma unroll
    for (int j = 0; j < 3; ++j) acc[i][j] = (f32x4){0.f, 0.f, 0.f, 0.f};

  // prologue: stage k=[0,64) into buffer 0 (two 32-col panels)
#pragma unroll
  for (int p = 0; p < 2; ++p) {
#pragma unroll
    for (int it = 0; it < 2; ++it) {
      int c = wave * 2 + it;
      int r = c * 16 + lr;
      size_t ga = (size_t)(m0 + r) * K + p * 32 + gj * 8;
      gload16(&Ah[ga], &sA[0][p * 4096 + c * 512]);
    }
#pragma unroll
    for (int it = 0; it < 2; ++it) {
      int c = wave + it * 4;
      if (c < 6) {
        int r = c * 16 + lr;
        size_t gb = (size_t)(n0 + r) * K + p * 32 + gj * 8;
        gload16(&Bh[gb], &sB[0][p * 3072 + c * 512]);
      }
    }
  }
  __syncthreads();

  int cur = 0;
  for (int k0 = 0; k0 < K; k0 += 64, cur ^= 1) {
    if (k0 + 64 < K) {
      const int kn = k0 + 64;
#pragma unroll
      for (int p = 0; p < 2; ++p) {
#pragma unroll
        for (int it = 0; it < 2; ++it) {
          int c = wave * 2 + it;
          int r = c * 16 + lr;
          size_t ga = (size_t)(m0 + r) * K + kn + p * 32 + gj * 8;
          gload16(&Ah[ga], &sA[cur ^ 1][p * 4096 + c * 512]);
        }
#pragma unroll
        for (int it = 0; it < 2; ++it) {
          int c = wave + it * 4;
          if (c < 6) {
            int r = c * 16 + lr;
            size_t gb = (size_t)(n0 + r) * K + kn + p * 32 + gj * 8;
            gload16(&Bh[gb], &sB[cur ^ 1][p * 3072 + c * 512]);
          }
        }
      }
    }
    const int sw = (quad ^ (l16 & 3)) * 8;
#pragma unroll
    for (int kk = 0; kk < 2; ++kk) {  // k-ascending panels -> bit-identical
      f16x8 fa[4], fb[3];
#pragma unroll
      for (int i = 0; i < 4; ++i)
        fa[i] = *(f16x8*)&sA[cur][kk * 4096 + (wm * 64 + i * 16 + l16) * 32 + sw];
#pragma unroll
      for (int j = 0; j < 3; ++j)
        fb[j] = *(f16x8*)&sB[cur][kk * 3072 + (wn * 48 + j * 16 + l16) * 32 + sw];
#pragma unroll
      for (int i = 0; i < 4; ++i)
#pragma unroll
        for (int j = 0; j < 3; ++j)
          acc[i][j] = __builtin_amdgcn_mfma_f32_16x16x32_f16(fa[i], fb[j], acc[i][j], 0, 0, 0);
    }
    __syncthreads();
  }
#pragma unroll
  for (int i = 0; i < 4; ++i) {
#pragma unroll
    for (int j = 0; j < 3; ++j) {
      int row = m0 + wm * 64 + i * 16 + quad * 4;
      int col = n0 + wn * 48 + j * 16 + l16;
      float bv = bias[col];
      if (col < NQ) {
#pragma unroll
        for (int r = 0; r < 4; ++r) {
          size_t o = (size_t)(row + r) * NQ + col;
          Qh[o] = f2h(acc[i][j][r] + bv);  // fp16 Q
        }
      } else if (col < NQ + NKV) {
        int c = col - NQ;
        size_t ob = ((size_t)(c >> 7) * S) * HD + (c & 127);
#pragma unroll
        for (int r = 0; r < 4; ++r) {
          size_t o = ob + (size_t)(row + r) * HD;
          Kh[o] = f2h(acc[i][j][r] + bv);  // fp16 K
        }
      } else {
        int c = col - NQ - NKV;
        ushort4v pv;
#pragma unroll
        for (int r = 0; r < 4; ++r) pv[r] = f2h(acc[i][j][r] + bv);  // fp16 V
        *(ushort4v*)&Vt[((size_t)(c >> 7) * HD + (c & 127)) * S + row] = pv;
      }
    }
  }
}

// ---------------------------------------------------------------------------
// fused post-attention kernel (verified R21): oproj 128x64 (512 blocks,
// 2/CU) + 464 cur blocks.
// ---------------------------------------------------------------------------
__global__ __launch_bounds__(256) void fuse_post(
    const unsigned short* __restrict__ AOh, const unsigned short* __restrict__ OTh,
    float* __restrict__ C,
    const unsigned short* __restrict__ Eg, const float* __restrict__ lbuf,
    float* __restrict__ cur) {
  __shared__ __align__(16) unsigned char smem[24576];
  const int bid = blockIdx.x;
  const int tid = threadIdx.x;
  if (bid < 512) {
    unsigned short* sAb = (unsigned short*)smem;        // 2 x 4096 ushort
    unsigned short* sBb = (unsigned short*)smem + 8192; // 2 x 2048 ushort
    const int lane = tid & 63, wave = tid >> 6;
    const int wm = wave >> 1, wn = wave & 1;
    const int quad = lane >> 4, l16 = lane & 15;
    const int m0 = (bid >> 5) * 128, n0 = (bid & 31) * 64;
    const int K = NQ, N = D;
    const int lr = lane >> 2;
    const int gj = (lane & 3) ^ (lr & 3);

    f32x4 acc[4][2];
#pragma unroll
    for (int i = 0; i < 4; ++i)
#pragma unroll
      for (int j = 0; j < 2; ++j) acc[i][j] = (f32x4){0.f, 0.f, 0.f, 0.f};

#pragma unroll
    for (int it = 0; it < 2; ++it) {
      int c = wave * 2 + it;
      int r = c * 16 + lr;
      size_t ga = (size_t)(m0 + r) * K + gj * 8;
      gload16(&AOh[ga], &sAb[c * 512]);
    }
    {
      int r = wave * 16 + lr;
      size_t gb = (size_t)(n0 + r) * K + gj * 8;
      gload16(&OTh[gb], &sBb[wave * 512]);
    }
    __syncthreads();

    int cb = 0;
    for (int k0 = 0; k0 < K; k0 += 32, cb ^= 1) {
      if (k0 + 32 < K) {
        const int kn = k0 + 32;
#pragma unroll
        for (int it = 0; it < 2; ++it) {
          int c = wave * 2 + it;
          int r = c * 16 + lr;
          size_t ga = (size_t)(m0 + r) * K + kn + gj * 8;
          gload16(&AOh[ga], &sAb[(cb ^ 1) * 4096 + c * 512]);
        }
        {
          int r = wave * 16 + lr;
          size_t gb = (size_t)(n0 + r) * K + kn + gj * 8;
          gload16(&OTh[gb], &sBb[(cb ^ 1) * 2048 + wave * 512]);
        }
      }
      const int sw = (quad ^ (l16 & 3)) * 8;
      bf16x8 fa[4], fb[2];
#pragma unroll
      for (int i = 0; i < 4; ++i)
        fa[i] = *(bf16x8*)&sAb[cb * 4096 + (wm * 64 + i * 16 + l16) * 32 + sw];
#pragma unroll
      for (int j = 0; j < 2; ++j)
        fb[j] = *(bf16x8*)&sBb[cb * 2048 + (wn * 32 + j * 16 + l16) * 32 + sw];
#pragma unroll
      for (int i = 0; i < 4; ++i)
#pragma unroll
        for (int j = 0; j < 2; ++j)
          acc[i][j] = __builtin_amdgcn_mfma_f32_16x16x32_bf16(fa[i], fb[j], acc[i][j], 0, 0, 0);
      __syncthreads();
    }
#pragma unroll
    for (int i = 0; i < 4; ++i)
#pragma unroll
      for (int j = 0; j < 2; ++j) {
        int row = m0 + wm * 64 + i * 16 + quad * 4;
        int col = n0 + wn * 32 + j * 16 + l16;
#pragma unroll
        for (int r = 0; r < 4; ++r)
          C[(size_t)(row + r) * N + col] = acc[i][j][r];
      }
  } else {
    const int bid2 = bid - 512;
    const int kt = bid2 % 29;   // 0..28
    const int h  = bid2 / 29;   // 0..15
    const int c8 = tid & 7, qg = tid >> 3;
    float acc[8];
#pragma unroll
    for (int j = 0; j < 8; ++j) acc[j] = 0.f;
    const size_t hb = (size_t)h * NTILE_H;
    for (int qt = kt; qt < 32; ++qt) {
      size_t tb = (hb + (size_t)(qt * (qt + 1) / 2) + kt) * 4096;
      float li0 = 1.0f / lbuf[h * S + qt * 64 + qg];
      float li1 = 1.0f / lbuf[h * S + qt * 64 + 32 + qg];
      f16x8 e0 = *(const f16x8*)&Eg[tb + (size_t)qg * 64 + c8 * 8];
      f16x8 e1 = *(const f16x8*)&Eg[tb + (size_t)(32 + qg) * 64 + c8 * 8];
#pragma unroll
      for (int j = 0; j < 8; ++j)
        acc[j] += (float)e0[j] * li0 + (float)e1[j] * li1;
    }
    float (*red)[8] = (float(*)[8])smem;
#pragma unroll
    for (int j = 0; j < 8; ++j) red[tid][j] = acc[j];
    __syncthreads();
    if (tid < 64) {
      int cc = tid >> 3, j = tid & 7;
      float s = 0.f;
#pragma unroll
      for (int g = 0; g < 32; ++g) s += red[cc + 8 * g][j];
      cur[h * S + kt * 64 + cc * 8 + j] = s;
    }
  }
}

// ---------------------------------------------------------------------------
// Plain bf16 GEMM (oproj) — FALLBACK only (no-E path).
// ---------------------------------------------------------------------------
__global__ __launch_bounds__(256) void gemm_bf16(
    const unsigned short* __restrict__ Ah, const unsigned short* __restrict__ Bh,
    float* __restrict__ C, int M, int N, int K) {
  __shared__ __align__(16) unsigned short sA[2][128 * 32];
  __shared__ __align__(16) unsigned short sB[2][128 * 32];
  const int tid = threadIdx.x;
  const int lane = tid & 63, wave = tid >> 6;
  const int wm = wave >> 1, wn = wave & 1;
  const int quad = lane >> 4, l16 = lane & 15;
  const int m0 = blockIdx.y * 128, n0 = blockIdx.x * 128;
  const int lr = lane >> 2;
  const int gj = (lane & 3) ^ (lr & 3);

  f32x4 acc[4][4];
#pragma unroll
  for (int i = 0; i < 4; ++i)
#pragma unroll
    for (int j = 0; j < 4; ++j) acc[i][j] = (f32x4){0.f, 0.f, 0.f, 0.f};

#pragma unroll
  for (int it = 0; it < 2; ++it) {
    int c = wave * 2 + it;
    int r = c * 16 + lr;
    size_t ga = (size_t)(m0 + r) * K + gj * 8;
    size_t gb = (size_t)(n0 + r) * K + gj * 8;
    gload16(&Ah[ga], &sA[0][c * 512]);
    gload16(&Bh[gb], &sB[0][c * 512]);
  }
  __syncthreads();

  int cur = 0;
  for (int k0 = 0; k0 < K; k0 += 32, cur ^= 1) {
    if (k0 + 32 < K) {
      const int kn = k0 + 32;
#pragma unroll
      for (int it = 0; it < 2; ++it) {
        int c = wave * 2 + it;
        int r = c * 16 + lr;
        size_t ga = (size_t)(m0 + r) * K + kn + gj * 8;
        size_t gb = (size_t)(n0 + r) * K + kn + gj * 8;
        gload16(&Ah[ga], &sA[cur ^ 1][c * 512]);
        gload16(&Bh[gb], &sB[cur ^ 1][c * 512]);
      }
    }
    const int sw = (quad ^ (l16 & 3)) * 8;
    bf16x8 fa[4], fb[4];
#pragma unroll
    for (int i = 0; i < 4; ++i) {
      fa[i] = *(bf16x8*)&sA[cur][(wm * 64 + i * 16 + l16) * 32 + sw];
      fb[i] = *(bf16x8*)&sB[cur][(wn * 64 + i * 16 + l16) * 32 + sw];
    }
#pragma unroll
    for (int i = 0; i < 4; ++i)
#pragma unroll
      for (int j = 0; j < 4; ++j)
        acc[i][j] = __builtin_amdgcn_mfma_f32_16x16x32_bf16(fa[i], fb[j], acc[i][j], 0, 0, 0);
    __syncthreads();
  }
#pragma unroll
  for (int i = 0; i < 4; ++i)
#pragma unroll
    for (int j = 0; j < 4; ++j) {
      int row = m0 + wm * 64 + i * 16 + quad * 4;
      int col = n0 + wn * 64 + j * 16 + l16;
#pragma unroll
      for (int r = 0; r < 4; ++r)
        C[(size_t)(row + r) * N + col] = acc[i][j][r];
    }
}

// ---------------------------------------------------------------------------
// MFMA flash attention (verified R18/R22 — R24's double-buffer reverted:
// measured neutral within noise while costing the 3-blocks/CU LDS headroom).
// 1-term fp16 QK^T, 512 blocks, anti-diagonal remap, register prefetch,
// E streamed to global.
// ---------------------------------------------------------------------------
__global__ __launch_bounds__(256) void attn_mfma(
    const unsigned short* __restrict__ Qh,
    const unsigned short* __restrict__ Kh,
    const unsigned short* __restrict__ Vt, unsigned short* __restrict__ AOh,
    float* __restrict__ lbuf, unsigned short* __restrict__ Eg) {
  const int x = blockIdx.x;
  const int base = x & 255;
  const int qt0 = base & 31, h0 = base >> 5;
  const int qt = (x < 256) ? qt0 : 31 - qt0;
  const int h  = (x < 256) ? h0 : h0 + 8;
  const int kvh = h / GROUPS;
  const int tid = threadIdx.x;
  const int lane = tid & 63, w = tid >> 6;
  const int quad = lane >> 4, l16 = lane & 15;
  const int q0 = qt * 64;

  __shared__ __align__(16) unsigned short smem[22528];  // 45056 B
  unsigned short* sQ  = smem;            // 64 x 136 (8704)
  unsigned short* sK  = smem;            // reuse after Q frags read
  unsigned short* sVt = smem + 8704;     // 128 x 72 (9216)
  unsigned short* sP  = smem + 17920;    // 4 waves x 16 x 72 (4608)

  const size_t ebase = ((size_t)h * NTILE_H + (size_t)(qt * (qt + 1) / 2)) * 4096;

  ushort8 pK[4], pV[4];
#pragma unroll
  for (int it = 0; it < 4; ++it) {
    int idx = tid + it * 256;
    int r = idx >> 4, c8 = idx & 15;
    size_t g = ((size_t)kvh * S + r) * HD + c8 * 8;
    pK[it] = *(const ushort8*)&Kh[g];
  }
#pragma unroll
  for (int it = 0; it < 4; ++it) {
    int idx = tid + it * 256;
    int d = idx >> 3, c8 = idx & 7;
    size_t g = ((size_t)kvh * HD + d) * S + c8 * 8;
    pV[it] = *(const ushort8*)&Vt[g];
  }

#pragma unroll
  for (int it = 0; it < 4; ++it) {
    int idx = tid + it * 256;
    int r = idx >> 4, c8 = idx & 15;
    size_t g = (size_t)(q0 + r) * NQ + h * HD + c8 * 8;
    *(ushort8*)&sQ[r * 136 + c8 * 8] = *(const ushort8*)&Qh[g];
  }
  __syncthreads();
  f16x8 fq[4];
#pragma unroll
  for (int d4 = 0; d4 < 4; ++d4)
    fq[d4] = *(f16x8*)&sQ[(w * 16 + l16) * 136 + d4 * 32 + quad * 8];

  f32x4 O[8];
#pragma unroll
  for (int jn = 0; jn < 8; ++jn) O[jn] = (f32x4){0.f, 0.f, 0.f, 0.f};
  float l_[4] = {0.f, 0.f, 0.f, 0.f};  // per-lane partials (reduced after loop)

  const int row_l = w * 16 + quad * 4;
  const int wbase = w * 1152;

  for (int kt = 0; kt <= qt; ++kt) {
    __syncthreads();
#pragma unroll
    for (int it = 0; it < 4; ++it) {
      int idx = tid + it * 256;
      int r = idx >> 4, c8 = idx & 15;
      *(ushort8*)&sK[r * 136 + c8 * 8] = pK[it];
    }
#pragma unroll
    for (int it = 0; it < 4; ++it) {
      int idx = tid + it * 256;
      int d = idx >> 3, c8 = idx & 7;
      *(ushort8*)&sVt[d * 72 + c8 * 8] = pV[it];
    }
    __syncthreads();
    if (kt < qt) {
#pragma unroll
      for (int it = 0; it < 4; ++it) {
        int idx = tid + it * 256;
        int r = idx >> 4, c8 = idx & 15;
        size_t g = ((size_t)kvh * S + (kt + 1) * 64 + r) * HD + c8 * 8;
        pK[it] = *(const ushort8*)&Kh[g];
      }
#pragma unroll
      for (int it = 0; it < 4; ++it) {
        int idx = tid + it * 256;
        int d = idx >> 3, c8 = idx & 7;
        size_t g = ((size_t)kvh * HD + d) * S + (kt + 1) * 64 + c8 * 8;
        pV[it] = *(const ushort8*)&Vt[g];
      }
    }

    f32x4 sc[4];
#pragma unroll
    for (int j = 0; j < 4; ++j) sc[j] = (f32x4){0.f, 0.f, 0.f, 0.f};
#pragma unroll
    for (int d4 = 0; d4 < 4; ++d4) {
#pragma unroll
      for (int j = 0; j < 4; ++j) {
        f16x8 bk = *(f16x8*)&sK[(j * 16 + l16) * 136 + d4 * 32 + quad * 8];
        sc[j] = __builtin_amdgcn_mfma_f32_16x16x32_f16(fq[d4], bk, sc[j], 0, 0, 0);
      }
    }
    const bool diag = (kt == qt);
#pragma unroll
    for (int j = 0; j < 4; ++j) {
      int col_l = j * 16 + l16;
#pragma unroll
      for (int r = 0; r < 4; ++r) {
        float v = sc[j][r] * SCALE;
        if (diag && col_l > row_l + r) v = -INFINITY;
        float p = __expf(v);
        sc[j][r] = p;
        l_[r] += p;
      }
    }
#pragma unroll
    for (int j = 0; j < 4; ++j)
#pragma unroll
      for (int r = 0; r < 4; ++r)
        sP[wbase + (quad * 4 + r) * 72 + j * 16 + l16] = f2h(sc[j][r]);  // fp16 P

    if (Eg) {
      size_t tb = ebase + (size_t)kt * 4096;
#pragma unroll
      for (int it2 = 0; it2 < 2; ++it2) {
        int ci = lane + it2 * 64;
        int row = ci >> 3, cc = ci & 7;
        *(ushort8*)&Eg[tb + (size_t)(w * 16 + row) * 64 + cc * 8] =
            *(ushort8*)&sP[wbase + row * 72 + cc * 8];
      }
    }

    f16x8 ap0 = *(f16x8*)&sP[wbase + l16 * 72 + quad * 8];
    f16x8 ap1 = *(f16x8*)&sP[wbase + l16 * 72 + 32 + quad * 8];
#pragma unroll
    for (int jn = 0; jn < 8; ++jn) {
      f16x8 bv0 = *(f16x8*)&sVt[(jn * 16 + l16) * 72 + quad * 8];
      f16x8 bv1 = *(f16x8*)&sVt[(jn * 16 + l16) * 72 + 32 + quad * 8];
      O[jn] = __builtin_amdgcn_mfma_f32_16x16x32_f16(ap0, bv0, O[jn], 0, 0, 0);
      O[jn] = __builtin_amdgcn_mfma_f32_16x16x32_f16(ap1, bv1, O[jn], 0, 0, 0);
    }
  }
  // single lane-reduce of l partials (within 16-lane groups)
#pragma unroll
  for (int off = 1; off < 16; off <<= 1)
#pragma unroll
    for (int r = 0; r < 4; ++r) l_[r] += __shfl_xor(l_[r], off);
  float linv[4];
#pragma unroll
  for (int r = 0; r < 4; ++r) linv[r] = 1.0f / l_[r];
#pragma unroll
  for (int jn = 0; jn < 8; ++jn)
#pragma unroll
    for (int r = 0; r < 4; ++r)
      AOh[(size_t)(q0 + row_l + r) * NQ + h * HD + jn * 16 + l16] =
          f2b(O[jn][r] * linv[r]);
  if (l16 == 0) {
#pragma unroll
    for (int r = 0; r < 4; ++r)
      lbuf[h * S + q0 + row_l + r] = l_[r];
  }
}

// ---------------------------------------------------------------------------
// MFMA cur pass (FALLBACK when workspace too small for E buffer), fp16 Q/K.
// ---------------------------------------------------------------------------
__global__ __launch_bounds__(256) void cur_mfma(
    const unsigned short* __restrict__ Qh,
    const unsigned short* __restrict__ Kh,
    const float* __restrict__ lbuf, float* __restrict__ cur) {
  const int x = blockIdx.x;
  const int base = x & 255;
  const int kt0 = base & 31, h0 = base >> 5;
  const int kt = (x < 256) ? kt0 : 31 - kt0;
  const int h  = (x < 256) ? h0 : h0 + 8;
  const int kvh = h / GROUPS;
  const int tid = threadIdx.x;
  const int lane = tid & 63, w = tid >> 6;
  const int quad = lane >> 4, l16 = lane & 15;

  __shared__ __align__(16) unsigned short sKh[8704];
  __shared__ __align__(16) unsigned short sQh[8704];
  __shared__ float slinv[64];

#pragma unroll
  for (int it = 0; it < 4; ++it) {
    int idx = tid + it * 256;
    int r = idx >> 4, c8 = idx & 15;
    size_t g = ((size_t)kvh * S + kt * 64 + r) * HD + c8 * 8;
    *(ushort8*)&sKh[r * 136 + c8 * 8] = *(const ushort8*)&Kh[g];
  }
  __syncthreads();
  f16x8 fk[4];
#pragma unroll
  for (int d4 = 0; d4 < 4; ++d4)
    fk[d4] = *(f16x8*)&sKh[(w * 16 + l16) * 136 + d4 * 32 + quad * 8];

  const int krow_l = w * 16 + quad * 4;
  float csum[4] = {0.f, 0.f, 0.f, 0.f};

  ushort8 pQ[4];
  float pli = 0.f;
#pragma unroll
  for (int it = 0; it < 4; ++it) {
    int idx = tid + it * 256;
    int r = idx >> 4, c8 = idx & 15;
    size_t g = (size_t)(kt * 64 + r) * NQ + h * HD + c8 * 8;
    pQ[it] = *(const ushort8*)&Qh[g];
  }
  if (tid < 64) pli = 1.0f / lbuf[h * S + kt * 64 + tid];

  for (int qt = kt; qt < S / 64; ++qt) {
    __syncthreads();
#pragma unroll
    for (int it = 0; it < 4; ++it) {
      int idx = tid + it * 256;
      int r = idx >> 4, c8 = idx & 15;
      *(ushort8*)&sQh[r * 136 + c8 * 8] = pQ[it];
    }
    if (tid < 64) slinv[tid] = pli;
    __syncthreads();
    if (qt + 1 < S / 64) {
#pragma unroll
      for (int it = 0; it < 4; ++it) {
        int idx = tid + it * 256;
        int r = idx >> 4, c8 = idx & 15;
        size_t g = (size_t)((qt + 1) * 64 + r) * NQ + h * HD + c8 * 8;
        pQ[it] = *(const ushort8*)&Qh[g];
      }
      if (tid < 64) pli = 1.0f / lbuf[h * S + (qt + 1) * 64 + tid];
    }
    f32x4 sc[4];
#pragma unroll
    for (int j = 0; j < 4; ++j) sc[j] = (f32x4){0.f, 0.f, 0.f, 0.f};
#pragma unroll
    for (int d4 = 0; d4 < 4; ++d4) {
#pragma unroll
      for (int j = 0; j < 4; ++j) {
        f16x8 bq = *(f16x8*)&sQh[(j * 16 + l16) * 136 + d4 * 32 + quad * 8];
        sc[j] = __builtin_amdgcn_mfma_f32_16x16x32_f16(fk[d4], bq, sc[j], 0, 0, 0);
      }
    }
    const bool diag = (qt == kt);
#pragma unroll
    for (int j = 0; j < 4; ++j) {
      int qcol_l = j * 16 + l16;
      float lv = slinv[qcol_l];
#pragma unroll
      for (int r = 0; r < 4; ++r) {
        float p = __expf(sc[j][r] * SCALE) * lv;
        if (diag && (krow_l + r) > qcol_l) p = 0.f;
        csum[r] += p;
      }
    }
  }
#pragma unroll
  for (int off = 1; off < 16; off <<= 1)
#pragma unroll
    for (int r = 0; r < 4; ++r) csum[r] += __shfl_xor(csum[r], off);
  if (l16 == 0) {
#pragma unroll
    for (int r = 0; r < 4; ++r)
      cur[h * S + kt * 64 + krow_l + r] = csum[r];
  }
}

// ---------------------------------------------------------------------------
// top-k + mask (verified R14).
// ---------------------------------------------------------------------------
__global__ __launch_bounds__(256) void topk_kernel(
    const float* __restrict__ cur, float* __restrict__ mask) {
  const int h = blockIdx.x;
  const int tid = threadIdx.x;
  const int lane = tid & 63, w = tid >> 6;
  __shared__ unsigned uv[SKEEP];
  __shared__ int redw[4];
  __shared__ int wsum[4];

  for (int i = tid; i < SKEEP; i += 256) uv[i] = __float_as_uint(cur[h * S + i]);
  __syncthreads();

  unsigned lo = 0u, hi = 0xffffffffu;
  while (lo < hi) {
    unsigned mid = (unsigned)((((unsigned long long)lo + hi) + 1ull) >> 1);
    int c = 0;
    for (int i = tid; i < SKEEP; i += 256) c += (uv[i] >= mid) ? 1 : 0;
#pragma unroll
    for (int off = 1; off < 64; off <<= 1) c += __shfl_xor(c, off);
    if (lane == 0) redw[w] = c;
    __syncthreads();
    int cnt = redw[0] + redw[1] + redw[2] + redw[3];
    __syncthreads();
    if (cnt >= HEAVY) lo = mid; else hi = mid - 1;
  }
  const unsigned vk = lo;
  int c = 0;
  for (int i = tid; i < SKEEP; i += 256) c += (uv[i] > vk) ? 1 : 0;
#pragma unroll
  for (int off = 1; off < 64; off <<= 1) c += __shfl_xor(c, off);
  if (lane == 0) redw[w] = c;
  __syncthreads();
  const int cgt = redw[0] + redw[1] + redw[2] + redw[3];
  const int rem = HEAVY - cgt;

  for (int j = tid; j < MASKC; j += 256)
    mask[(size_t)h * MASKC + j] = (j >= MASKC - RECENT) ? 1.0f : 0.0f;
  __syncthreads();
  for (int i = tid; i < SKEEP; i += 256)
    if (uv[i] > vk) mask[(size_t)h * MASKC + i] = 1.0f;

  // parallel tie fill: blocked partition preserves index order
  constexpr int PER = (SKEEP + 255) / 256;  // 8
  int i0 = tid * PER;
  int i1 = i0 + PER;
  if (i0 > SKEEP) i0 = SKEEP;
  if (i1 > SKEEP) i1 = SKEEP;
  int myT = 0;
  for (int i = i0; i < i1; ++i) myT += (uv[i] == vk) ? 1 : 0;
  int v = myT;
#pragma unroll
  for (int off = 1; off < 64; off <<= 1) {
    int t = __shfl_up(v, off);
    if (lane >= off) v += t;
  }
  if (lane == 63) wsum[w] = v;
  __syncthreads();
  int wOff = 0;
  for (int k = 0; k < w; ++k) wOff += wsum[k];
  int excl = wOff + v - myT;
  for (int i = i0; i < i1; ++i) {
    if (uv[i] == vk) {
      if (excl < rem) mask[(size_t)h * MASKC + i] = 1.0f;
      ++excl;
    }
  }
}

// ---------------------------------------------------------------------------
extern "C" void kernel_launch(void* const* d_in, const int* in_sizes, int n_in,
                              void* d_out, int out_size, void* d_ws,
                              size_t ws_size, hipStream_t stream) {
  const float* hs  = (const float*)d_in[0];
  const float* q_w = (const float*)d_in[1];
  const float* q_b = (const float*)d_in[2];
  const float* k_w = (const float*)d_in[3];
  const float* k_b = (const float*)d_in[4];
  const float* v_w = (const float*)d_in[5];
  const float* v_b = (const float*)d_in[6];
  const float* o_w = (const float*)d_in[7];

  char* ws = (char*)d_ws;
  unsigned short* Qh   = (unsigned short*)(ws + 0);
  unsigned short* Kh   = (unsigned short*)(ws + 16777216);
  unsigned short* Vt   = (unsigned short*)(ws + 20971520);
  unsigned short* AOh  = (unsigned short*)(ws + 25165824);
  float* lb   = (float*)(ws + 33685504);
  float* cur  = (float*)(ws + 33816576);
  float* bcat = (float*)(ws + 33947648);
  char* pool = ws + 33959936;
  unsigned short* hsh = (unsigned short*)pool;                 // 8.4 MB fp16
  unsigned short* WTh = (unsigned short*)(pool + 16777216);    // 12.6 MB fp16
  unsigned short* OTh = (unsigned short*)(pool + 41943040);    // 8.4 MB bf16

  // packed-causal E buffer (16 heads x 528 tiles x 64x64 fp16 = 69.2 MB)
  const size_t E_OFF = 84291584ull;               // end of pool
  const size_t E_SZ  = (size_t)H * NTILE_H * 4096 * 2;  // 69,206,016
  const bool use_e = (ws_size >= E_OFF + E_SZ);
  unsigned short* Eg = use_e ? (unsigned short*)(ws + E_OFF) : nullptr;

  float* outp  = (float*)d_out;
  float* maskp = outp + (size_t)S * D;

  dim3 blk(256);
  prep_all<<<dim3(3084), blk, 0, stream>>>(hs, q_w, k_w, v_w, o_w, q_b, k_b,
                                           v_b, hsh, WTh, OTh, bcat);
  gemm_qkv<<<dim3(N3 / 96, S / 128), blk, 0, stream>>>(
      hsh, WTh, bcat, Qh, Kh, Vt, S, N3, D);
  attn_mfma<<<dim3(512), blk, 0, stream>>>(Qh, Kh, Vt, AOh, lb, Eg);
  if (use_e) {
    fuse_post<<<dim3(512 + 29 * 16), blk, 0, stream>>>(AOh, OTh, outp, Eg, lb,
                                                       cur);
    topk_kernel<<<dim3(H), blk, 0, stream>>>(cur, maskp);
  } else {
    cur_mfma<<<dim3(512), blk, 0, stream>>>(Qh, Kh, lb, cur);
    topk_kernel<<<dim3(H), blk, 0, stream>>>(cur, maskp);
    gemm_bf16<<<dim3(D / 128, S / 128), blk, 0, stream>>>(AOh, OTh, outp, S, D,
                                                          NQ);
  }
}